// Round 4
// baseline (251.340 us; speedup 1.0000x reference)
//
#include <hip/hip_runtime.h>
#include <hip/hip_bf16.h>

// GAT layer, B=2 N=4096 F_IN=256 F_OUT=64 H=4.
// prep: x = h@W, xT bf16 [b][f][n], elT/erT pre-scaled by log2e.
// main: I=64 rows/block, JT=64, 4-way j-split (grid 512), wave=head, ring-3
//       counted-vmcnt; xt/er frags hoisted per tile, reused over 4 row-sets;
//       swapped PV (A=xt, B=P) -> acc rows = f -> float4 partial stores.
// fin:  combine 4 j-partials, /denom, +bias, elu.

#define NN 4096
#define NH 4
#define JT 64
#define IT 64
#define NSET 4
#define NJQ 4
#define NTS ((NN / NJQ) / JT)   // 16
#define LOG2E 1.4426950408889634f

typedef __bf16 bf16x8 __attribute__((ext_vector_type(8)));
typedef unsigned short ushortx8 __attribute__((ext_vector_type(8)));
typedef unsigned short us4 __attribute__((ext_vector_type(4)));
typedef float f32x4 __attribute__((ext_vector_type(4)));

__device__ __forceinline__ void gload_lds16(const void* g, void* lds) {
  __builtin_amdgcn_global_load_lds(
      (const __attribute__((address_space(1))) void*)g,
      (__attribute__((address_space(3))) void*)lds, 16, 0, 0);
}

__device__ __forceinline__ unsigned short f2bf(float x) {
  __hip_bfloat16 hb = __float2bfloat16(x);
  return __builtin_bit_cast(unsigned short, hb);
}

#if __has_builtin(__builtin_amdgcn_exp2f)
#define EXP2F(x) __builtin_amdgcn_exp2f(x)
#else
#define EXP2F(x) exp2f(x)
#endif

// ---------------- kernel 1: prep (unchanged from round 3) ----------------
__global__ __launch_bounds__(256, 2) void gat_prep(
    const float* __restrict__ hmat, const float* __restrict__ W,
    const float* __restrict__ Wl, const float* __restrict__ Wr,
    unsigned short* __restrict__ xT, float* __restrict__ elT,
    float* __restrict__ erT)
{
  __shared__ __align__(16) float h_s[16][256];
  __shared__ float x_s[16][65];
  __shared__ float wlr_s[512];

  const int t  = threadIdx.x;
  const int wv = t >> 6;
  const int l  = t & 63;
  const int b  = blockIdx.x >> 8;
  const int i0 = (blockIdx.x & 255) << 4;

  {
    const float4* hsrc = (const float4*)(hmat + ((size_t)(b * NN + i0)) * 256);
    float4* hdst = (float4*)&h_s[0][0];
#pragma unroll
    for (int u = 0; u < 4; ++u) hdst[t + 256 * u] = hsrc[t + 256 * u];
    wlr_s[t]       = Wl[t];
    wlr_s[256 + t] = Wr[t];
  }
  __syncthreads();

  const int row0 = wv << 2;
  float acc[4] = {0.f, 0.f, 0.f, 0.f};
#pragma unroll 4
  for (int k4 = 0; k4 < 64; ++k4) {
    const float w0 = W[(k4 * 4 + 0) * 64 + l];
    const float w1 = W[(k4 * 4 + 1) * 64 + l];
    const float w2 = W[(k4 * 4 + 2) * 64 + l];
    const float w3 = W[(k4 * 4 + 3) * 64 + l];
#pragma unroll
    for (int rr = 0; rr < 4; ++rr) {
      const float4 hv = *(const float4*)&h_s[row0 + rr][k4 * 4];
      acc[rr] = fmaf(hv.x, w0, acc[rr]);
      acc[rr] = fmaf(hv.y, w1, acc[rr]);
      acc[rr] = fmaf(hv.z, w2, acc[rr]);
      acc[rr] = fmaf(hv.w, w3, acc[rr]);
    }
  }
#pragma unroll
  for (int rr = 0; rr < 4; ++rr) x_s[row0 + rr][l] = acc[rr];
  __syncthreads();

  if (t < 64) {
    const int row = t >> 2, hh = t & 3;
    float el = 0.f, er = 0.f;
#pragma unroll 8
    for (int f = 0; f < 64; ++f) {
      const float xv = x_s[row][f];
      el = fmaf(xv, wlr_s[hh * 64 + f], el);
      er = fmaf(xv, wlr_s[256 + hh * 64 + f], er);
    }
    elT[((size_t)b * NH + hh) * NN + i0 + row] = el * LOG2E;
    erT[((size_t)b * NH + hh) * NN + i0 + row] = er * LOG2E;
  }

  {
    const int f = t >> 2, q = t & 3;
    us4 pk;
#pragma unroll
    for (int rj = 0; rj < 4; ++rj) pk[rj] = f2bf(x_s[q * 4 + rj][f]);
    *(us4*)&xT[((size_t)(b * 64 + f)) * NN + i0 + q * 4] = pk;
  }
}

// ---------------- kernel 2: fused softmax + PV ----------------
// grid 512 = b(2) x itile(64) x jq(4); block 256, 4 waves, wave = head.
template <bool ATOMIC>
__global__ __launch_bounds__(256, 2) void gat_main(
    const int* __restrict__ adj, const unsigned short* __restrict__ xT,
    const float* __restrict__ elT, const float* __restrict__ erT,
    float* __restrict__ numP, float* __restrict__ denP)
{
  __shared__ __align__(16) int            adj_lds[3][IT * JT];  // 48 KB
  __shared__ __align__(16) unsigned short xt_lds[3][64 * JT];   // 24 KB
  __shared__ __align__(16) float          er_lds[3][NH * JT];   // 3 KB

  const int t = threadIdx.x;
  const int w = t >> 6;           // wave = head
  const int l = t & 63;
  const int b     = blockIdx.x >> 8;
  const int itile = (blockIdx.x & 255) >> 2;
  const int jq    = blockIdx.x & 3;
  const int i0    = itile << 6;
  const int j0b   = jq << 10;     // 1024-wide j range

  const int lrow = l & 15;
  const int lk   = l >> 4;

  float el_reg[NSET];
#pragma unroll
  for (int set = 0; set < NSET; ++set)
    el_reg[set] = elT[((size_t)b * NH + w) * NN + i0 + (set << 4) + lrow];

  // stage one 64-j tile into ring slot s. per-wave loads: w0-2: 6, w3: 7.
  auto issue_tile = [&](int j0, int s) {
#pragma unroll
    for (int g = 0; g < 4; ++g) {          // adj: 16 KB = 16 gloads, 4/wave
      const int gi = (w << 2) + g;
      const int r  = (gi << 2) + (l >> 4);
      gload_lds16(adj + ((size_t)(b * NN + i0 + r)) * NN + j0 +
                      ((((l & 15) ^ (r & 7))) << 2),
                  &adj_lds[s][gi << 8]);
    }
#pragma unroll
    for (int g = 0; g < 2; ++g) {          // xt: 8 KB = 8 gloads, 2/wave
      const int gi = (w << 1) + g;
      const int f  = (gi << 3) + (l >> 3);
      gload_lds16(xT + ((size_t)(b * 64 + f)) * NN + j0 +
                      ((((l & 7) ^ (f & 7))) << 3),
                  &xt_lds[s][gi << 9]);
    }
    if (w == 3) {                          // er: 1 KB = 1 gload
      const int h2 = l >> 4;
      gload_lds16(erT + ((size_t)b * NH + h2) * NN + j0 + ((l & 15) << 2),
                  &er_lds[s][0]);
    }
  };

  f32x4 acc[NSET][4] = {};
  f32x4 accd[NSET] = {};
  ushortx8 ones_u;
#pragma unroll
  for (int i = 0; i < 8; ++i) ones_u[i] = 0x3F80;
  const bf16x8 onesf = __builtin_bit_cast(bf16x8, ones_u);

  issue_tile(j0b, 0);
  issue_tile(j0b + JT, 1);

  for (int it = 0; it < NTS; ++it) {
    const int s = it % 3;
    if (it == NTS - 1) asm volatile("s_waitcnt vmcnt(0)" ::: "memory");
    else if (w < 3)    asm volatile("s_waitcnt vmcnt(6)" ::: "memory");
    else               asm volatile("s_waitcnt vmcnt(7)" ::: "memory");
    __builtin_amdgcn_s_barrier();
    __builtin_amdgcn_sched_barrier(0);

    if (it + 2 < NTS) issue_tile(j0b + (it + 2) * JT, (it + 2) % 3);

    // hoisted per-tile fragments (reused across all 4 row-sets)
    float4 er_f[2][2];
    bf16x8 Axt[2][4];
#pragma unroll
    for (int kc = 0; kc < 2; ++kc) {
      er_f[kc][0] = *(const float4*)&er_lds[s][(w << 6) + (kc << 5) + (lk << 3)];
      er_f[kc][1] = *(const float4*)&er_lds[s][(w << 6) + (kc << 5) + (lk << 3) + 4];
#pragma unroll
      for (int fq = 0; fq < 4; ++fq) {
        const int f = (fq << 4) + lrow;
        const int c = ((kc << 2) + lk) ^ (f & 7);
        Axt[kc][fq] = __builtin_bit_cast(
            bf16x8, *(const ushortx8*)&xt_lds[s][(f << 6) + (c << 3)]);
      }
    }

#pragma unroll
    for (int set = 0; set < NSET; ++set) {
      const int r  = (set << 4) + lrow;
      const int rb = r << 6;
      const int sw = r & 7;
#pragma unroll
      for (int kc = 0; kc < 2; ++kc) {
        const int cb = (kc << 3) + (lk << 1);
        const int4 aj0 = *(const int4*)&adj_lds[s][rb + ((cb ^ sw) << 2)];
        const int4 aj1 = *(const int4*)&adj_lds[s][rb + (((cb + 1) ^ sw) << 2)];
        const float4 er0 = er_f[kc][0];
        const float4 er1 = er_f[kc][1];

        ushortx8 pa;
#define SCORE(A_, E_, IDX) { \
        float s_  = el_reg[set] + (E_); \
        float lr_ = fmaxf(s_, 0.2f * s_); \
        float w_  = (A_) ? EXP2F(lr_) : 0.0f; \
        pa[IDX] = f2bf(w_); }
        SCORE(aj0.x, er0.x, 0) SCORE(aj0.y, er0.y, 1)
        SCORE(aj0.z, er0.z, 2) SCORE(aj0.w, er0.w, 3)
        SCORE(aj1.x, er1.x, 4) SCORE(aj1.y, er1.y, 5)
        SCORE(aj1.z, er1.z, 6) SCORE(aj1.w, er1.w, 7)
#undef SCORE

        const bf16x8 P = __builtin_bit_cast(bf16x8, pa);
        // swapped PV: D[f][i] = sum_j xt[f][j] * P[j][i]
        accd[set] = __builtin_amdgcn_mfma_f32_16x16x32_bf16(onesf, P, accd[set], 0, 0, 0);
#pragma unroll
        for (int fq = 0; fq < 4; ++fq)
          acc[set][fq] = __builtin_amdgcn_mfma_f32_16x16x32_bf16(
              Axt[kc][fq], P, acc[set][fq], 0, 0, 0);
      }
    }
  }

  // epilogue: C row = f = fq*16 + lk*4 + reg, col = i = set*16 + lrow
  if (ATOMIC) {
#pragma unroll
    for (int set = 0; set < NSET; ++set) {
      const size_t obase = ((size_t)(b * NN + i0 + (set << 4) + lrow) * NH + w) << 6;
#pragma unroll
      for (int fq = 0; fq < 4; ++fq)
#pragma unroll
        for (int rr = 0; rr < 4; ++rr)
          atomicAdd(&numP[obase + (fq << 4) + (lk << 2) + rr], acc[set][fq][rr]);
    }
    if (l < 16) {
#pragma unroll
      for (int set = 0; set < NSET; ++set)
        atomicAdd(&denP[((size_t)(b * NN + i0 + (set << 4) + l)) * NH + w],
                  accd[set][0]);
    }
  } else {
    float* nb = numP + (size_t)jq * (2u * NN * NH * 64);
#pragma unroll
    for (int set = 0; set < NSET; ++set) {
      const size_t obase = ((size_t)(b * NN + i0 + (set << 4) + lrow) * NH + w) << 6;
#pragma unroll
      for (int fq = 0; fq < 4; ++fq)
        *(float4*)&nb[obase + (fq << 4) + (lk << 2)] = (float4){
            acc[set][fq][0], acc[set][fq][1], acc[set][fq][2], acc[set][fq][3]};
    }
    if (l < 16) {
      float* db = denP + (size_t)jq * (2u * NN * NH);
#pragma unroll
      for (int set = 0; set < NSET; ++set)
        db[((size_t)(b * NN + i0 + (set << 4) + l)) * NH + w] = accd[set][0];
    }
  }
}

// ---------------- kernel 3: finalize ----------------
template <bool ATOMIC>
__global__ __launch_bounds__(256) void gat_fin(
    const float* __restrict__ numP, const float* __restrict__ denP,
    const float* __restrict__ bias, float* __restrict__ out)
{
  const int g  = blockIdx.x * 256 + threadIdx.x;     // 524288 threads
  const int f4 = (g & 15) << 2;
  float4 n;
  float d;
  if (ATOMIC) {
    n = *(const float4*)&out[(size_t)g * 4];
    d = denP[g >> 4];
  } else {
    n = (float4){0.f, 0.f, 0.f, 0.f};
    d = 0.f;
#pragma unroll
    for (int q = 0; q < NJQ; ++q) {
      const float4 nq = *(const float4*)&numP[(size_t)q * (2u * NN * NH * 64) + (size_t)g * 4];
      n.x += nq.x; n.y += nq.y; n.z += nq.z; n.w += nq.w;
      d += denP[(size_t)q * (2u * NN * NH) + (g >> 4)];
    }
  }
  const float inv = 1.0f / d;
  const float4 bv = *(const float4*)&bias[f4];
  float4 v = {n.x * inv + bv.x, n.y * inv + bv.y,
              n.z * inv + bv.z, n.w * inv + bv.w};
  v.x = v.x > 0.f ? v.x : (__expf(v.x) - 1.f);
  v.y = v.y > 0.f ? v.y : (__expf(v.y) - 1.f);
  v.z = v.z > 0.f ? v.z : (__expf(v.z) - 1.f);
  v.w = v.w > 0.f ? v.w : (__expf(v.w) - 1.f);
  *(float4*)&out[(size_t)g * 4] = v;
}

extern "C" void kernel_launch(void* const* d_in, const int* in_sizes, int n_in,
                              void* d_out, int out_size, void* d_ws, size_t ws_size,
                              hipStream_t stream) {
  const int*   adj  = (const int*)d_in[0];
  const float* hmat = (const float*)d_in[1];
  const float* W    = (const float*)d_in[2];
  const float* Wl   = (const float*)d_in[3];
  const float* Wr   = (const float*)d_in[4];
  const float* bias = (const float*)d_in[5];
  float* out = (float*)d_out;

  char* wsb = (char*)d_ws;
  unsigned short* xT = (unsigned short*)wsb;                 // 1 MB
  float* elT = (float*)(wsb + 1048576);                      // 128 KB
  float* erT = (float*)(wsb + 1179648);                      // 128 KB
  float* den = (float*)(wsb + 1310720);                      // 4 x 128 KB
  float* num = (float*)(wsb + 1835008);                      // 4 x 8 MB
  const bool partial = ws_size >= 35389440ull;

  gat_prep<<<512, 256, 0, stream>>>(hmat, W, Wl, Wr, xT, elT, erT);

  if (partial) {
    gat_main<false><<<512, 256, 0, stream>>>(adj, xT, elT, erT, num, den);
    gat_fin<false><<<2048, 256, 0, stream>>>(num, den, bias, out);
  } else {
    hipMemsetAsync(out, 0, (size_t)out_size * 4, stream);
    hipMemsetAsync(den, 0, 131072, stream);
    gat_main<true><<<512, 256, 0, stream>>>(adj, xT, elT, erT, out, den);
    gat_fin<true><<<2048, 256, 0, stream>>>(num, den, bias, out);
  }
}